// Round 1
// baseline (767.301 us; speedup 1.0000x reference)
//
#include <hip/hip_runtime.h>
#include <math.h>

// Problem constants (from reference)
#define N_TOK  16384   // B*S = 4*4096
#define D_IN   1024
#define D_OUT  1024
#define N_CENT 1024

// Tiling for the distance kernel
#define BM 64
#define BN 64
#define BK 32
#define NT_M (N_TOK / BM)    // 256
#define NT_N (N_CENT / BN)   // 16

// ---------------------------------------------------------------------------
// Kernel 1/2: row squared norms (||x||^2 per token row, ||c||^2 per centroid)
// One wave (64 lanes) per row, 4 rows per 256-thread block.
// ---------------------------------------------------------------------------
__global__ __launch_bounds__(256) void rowsq_kernel(
    const float* __restrict__ x, float* __restrict__ out, int nrows)
{
    const int wave = threadIdx.x >> 6;   // 0..3
    const int lane = threadIdx.x & 63;
    const int row  = blockIdx.x * 4 + wave;
    if (row >= nrows) return;
    const float4* xr = (const float4*)(x + (size_t)row * D_IN);
    float s = 0.f;
#pragma unroll
    for (int i = 0; i < D_IN / 4 / 64; ++i) {   // 4 iterations
        float4 v = xr[lane + i * 64];
        s += v.x * v.x + v.y * v.y + v.z * v.z + v.w * v.w;
    }
#pragma unroll
    for (int off = 32; off > 0; off >>= 1) s += __shfl_down(s, off);
    if (lane == 0) out[row] = s;
}

// ---------------------------------------------------------------------------
// Kernel 3: tiled fp32 distance + per-tile argmin.
// Block = 256 threads as 16x16; each thread owns a 4x4 micro-tile.
// d2 = (x_sq - 2*g) + c_sq  -- exact same association as the numpy reference.
// Argmin scans centroid indices in increasing order with strict <, which
// reproduces numpy's first-occurrence tie-break.
// ---------------------------------------------------------------------------
__global__ __launch_bounds__(256) void dist_argmin_kernel(
    const float* __restrict__ X,       // [N_TOK][D_IN]
    const float* __restrict__ C,       // [N_CENT][D_IN]
    const float* __restrict__ x_sq,    // [N_TOK]
    const float* __restrict__ c_sq,    // [N_CENT]
    float* __restrict__ part_d2,       // [N_TOK][NT_N]
    int*   __restrict__ part_idx)      // [N_TOK][NT_N]
{
    __shared__ float Xs[BK][BM];
    __shared__ float Cs[BK][BN];
    __shared__ float red_d2[BM][16];
    __shared__ int   red_idx[BM][16];

    const int t  = threadIdx.x;
    const int tx = t & 15;
    const int ty = t >> 4;
    const int m0 = blockIdx.x * BM;
    const int n0 = blockIdx.y * BN;

    float acc[4][4];
#pragma unroll
    for (int i = 0; i < 4; ++i)
#pragma unroll
        for (int j = 0; j < 4; ++j) acc[i][j] = 0.f;

    const int lrow = t >> 2;   // 0..63 : row within the tile
    const int lc4  = t & 3;    // 0..3  : which float4 along k

    for (int k0 = 0; k0 < D_IN; k0 += BK) {
#pragma unroll
        for (int h = 0; h < 2; ++h) {
            const int c4 = lc4 + h * 4;    // 0..7  (8 float4 = 32 floats of k)
            float4 xv = *(const float4*)(X + (size_t)(m0 + lrow) * D_IN + k0 + c4 * 4);
            float4 cv = *(const float4*)(C + (size_t)(n0 + lrow) * D_IN + k0 + c4 * 4);
            Xs[c4 * 4 + 0][lrow] = xv.x; Xs[c4 * 4 + 1][lrow] = xv.y;
            Xs[c4 * 4 + 2][lrow] = xv.z; Xs[c4 * 4 + 3][lrow] = xv.w;
            Cs[c4 * 4 + 0][lrow] = cv.x; Cs[c4 * 4 + 1][lrow] = cv.y;
            Cs[c4 * 4 + 2][lrow] = cv.z; Cs[c4 * 4 + 3][lrow] = cv.w;
        }
        __syncthreads();
#pragma unroll
        for (int kk = 0; kk < BK; ++kk) {
            float4 xa = *(const float4*)&Xs[kk][ty * 4];
            float4 cb = *(const float4*)&Cs[kk][tx * 4];
            const float xs4[4] = {xa.x, xa.y, xa.z, xa.w};
            const float cs4[4] = {cb.x, cb.y, cb.z, cb.w};
#pragma unroll
            for (int i = 0; i < 4; ++i)
#pragma unroll
                for (int j = 0; j < 4; ++j)
                    acc[i][j] = fmaf(xs4[i], cs4[j], acc[i][j]);
        }
        __syncthreads();
    }

    // Per-thread argmin over its 4 centroids (increasing index -> strict <)
#pragma unroll
    for (int i = 0; i < 4; ++i) {
        const int m = m0 + ty * 4 + i;
        const float xq = x_sq[m];
        float bd = INFINITY;
        int   bi = n0 + tx * 4;   // overwritten on first compare (d2 < inf)
#pragma unroll
        for (int j = 0; j < 4; ++j) {
            const int n = n0 + tx * 4 + j;
            const float g  = acc[i][j];
            const float d2 = (xq - 2.0f * g) + c_sq[n];
            if (d2 < bd) { bd = d2; bi = n; }
        }
        red_d2[ty * 4 + i][tx]  = bd;
        red_idx[ty * 4 + i][tx] = bi;
    }
    __syncthreads();

    // Cross-thread reduce per token: scan tx in increasing order (indices
    // increase with tx), strict < keeps the first occurrence.
    if (t < BM) {
        float bd = red_d2[t][0];
        int   bi = red_idx[t][0];
#pragma unroll
        for (int q = 1; q < 16; ++q) {
            const float d = red_d2[t][q];
            if (d < bd) { bd = d; bi = red_idx[t][q]; }
        }
        const int m = m0 + t;
        part_d2[(size_t)m * NT_N + blockIdx.y]  = bd;
        part_idx[(size_t)m * NT_N + blockIdx.y] = bi;
    }
}

// ---------------------------------------------------------------------------
// Kernel 4: final argmin across the 16 centroid tiles (increasing tile order,
// strict <) fused with the table gather + bias. One block per token.
// ---------------------------------------------------------------------------
__global__ __launch_bounds__(256) void reduce_gather_kernel(
    const float* __restrict__ part_d2,
    const int*   __restrict__ part_idx,
    const float* __restrict__ table,   // [N_CENT][D_OUT]
    const float* __restrict__ bias,    // [D_OUT]
    float* __restrict__ out)           // [N_TOK][D_OUT]
{
    const int m = blockIdx.x;
    float bd = INFINITY;
    int   bi = 0;
#pragma unroll
    for (int q = 0; q < NT_N; ++q) {
        const float d = part_d2[(size_t)m * NT_N + q];
        if (d < bd) { bd = d; bi = part_idx[(size_t)m * NT_N + q]; }
    }
    const float4* tr = (const float4*)(table + (size_t)bi * D_OUT);
    const float4* br = (const float4*)bias;
    float4* orow = (float4*)(out + (size_t)m * D_OUT);
    const int tid = threadIdx.x;          // 0..255 ; 1024 floats = 256 float4
    float4 tv = tr[tid];
    float4 bv = br[tid];
    orow[tid] = make_float4(tv.x + bv.x, tv.y + bv.y, tv.z + bv.z, tv.w + bv.w);
}

// ---------------------------------------------------------------------------
// Launch
// ---------------------------------------------------------------------------
extern "C" void kernel_launch(void* const* d_in, const int* in_sizes, int n_in,
                              void* d_out, int out_size, void* d_ws, size_t ws_size,
                              hipStream_t stream)
{
    const float* X     = (const float*)d_in[0];   // [16384,1024]
    const float* C     = (const float*)d_in[1];   // [1024,1024]
    const float* table = (const float*)d_in[2];   // [1024,1024]
    const float* bias  = (const float*)d_in[3];   // [1024]
    float* out = (float*)d_out;

    // Workspace layout (floats): x_sq[16384] | c_sq[1024] | part_d2[16384*16]
    //                            | part_idx[16384*16]
    float* x_sq    = (float*)d_ws;
    float* c_sq    = x_sq + N_TOK;
    float* part_d2 = c_sq + N_CENT;
    int*   part_idx = (int*)(part_d2 + (size_t)N_TOK * NT_N);

    rowsq_kernel<<<N_TOK / 4, 256, 0, stream>>>(X, x_sq, N_TOK);
    rowsq_kernel<<<N_CENT / 4, 256, 0, stream>>>(C, c_sq, N_CENT);

    dim3 grid(NT_M, NT_N);
    dist_argmin_kernel<<<grid, 256, 0, stream>>>(X, C, x_sq, c_sq, part_d2, part_idx);

    reduce_gather_kernel<<<N_TOK, 256, 0, stream>>>(part_d2, part_idx, table, bias, out);
}

// Round 2
// 625.106 us; speedup vs baseline: 1.2275x; 1.2275x over previous
//
#include <hip/hip_runtime.h>
#include <math.h>

// Problem constants (from reference)
#define N_TOK  16384   // B*S = 4*4096
#define D_IN   1024
#define D_OUT  1024
#define N_CENT 1024

// Tiling for the distance kernel
#define BM 128
#define BN 128
#define BK 16
#define NT_M (N_TOK / BM)    // 128
#define NT_N (N_CENT / BN)   // 8

// LDS layout: k-major rows of BM(=BN) columns, with 4 floats of pad after
// every 8 columns (thread's 8 cols stay contiguous -> two aligned float4
// reads; 16 distinct read addresses/wave land 2-way on banks = free), and a
// row stride of 196 floats ( !≡ 0 mod 32, so staging writes with k varying
// are also 2-way = free). 196*4 = 784 bytes, 16B-aligned rows.
#define LDROW 196
// column c -> padded offset
__device__ __forceinline__ int cpad(int c) { return c + ((c >> 3) << 2); }

// ---------------------------------------------------------------------------
// Row squared norms (||x||^2 per row). One wave per row, 4 rows per block.
// ---------------------------------------------------------------------------
__global__ __launch_bounds__(256) void rowsq_kernel(
    const float* __restrict__ x, float* __restrict__ out, int nrows)
{
    const int wave = threadIdx.x >> 6;
    const int lane = threadIdx.x & 63;
    const int row  = blockIdx.x * 4 + wave;
    if (row >= nrows) return;
    const float4* xr = (const float4*)(x + (size_t)row * D_IN);
    float s = 0.f;
#pragma unroll
    for (int i = 0; i < D_IN / 4 / 64; ++i) {
        float4 v = xr[lane + i * 64];
        s += v.x * v.x + v.y * v.y + v.z * v.z + v.w * v.w;
    }
#pragma unroll
    for (int off = 32; off > 0; off >>= 1) s += __shfl_down(s, off);
    if (lane == 0) out[row] = s;
}

// ---------------------------------------------------------------------------
// Tiled fp32 distance + per-tile argmin. 256 threads as 16x16, each thread
// an 8x8 micro-tile (64 FMA per 4 ds_read_b128).
// d2 = (x_sq - 2*g) + c_sq  -- same association as the numpy reference.
// Argmin scans centroid indices ascending with strict < at every level
// (thread j-loop, cross-thread tx-loop, cross-tile q-loop) -> numpy
// first-occurrence tie-break.
// ---------------------------------------------------------------------------
__global__ __launch_bounds__(256) void dist_argmin_kernel(
    const float* __restrict__ X,       // [N_TOK][D_IN]
    const float* __restrict__ C,       // [N_CENT][D_IN]
    const float* __restrict__ x_sq,    // [N_TOK]
    const float* __restrict__ c_sq,    // [N_CENT]
    float* __restrict__ part_d2,       // [N_TOK][NT_N]
    int*   __restrict__ part_idx)      // [N_TOK][NT_N]
{
    // Arena: staging buffers, later reused for the argmin reduction.
    __shared__ float Xs[BK * LDROW];   // 3136 floats = 12544 B
    __shared__ float Cs[BK * LDROW];

    const int t  = threadIdx.x;
    const int tx = t & 15;             // centroid-dim thread coord
    const int ty = t >> 4;             // token-dim thread coord
    const int m0 = blockIdx.x * BM;
    const int n0 = blockIdx.y * BN;

    float acc[8][8];
#pragma unroll
    for (int i = 0; i < 8; ++i)
#pragma unroll
        for (int j = 0; j < 8; ++j) acc[i][j] = 0.f;

    // staging coords: 512 float4 per operand per k0-block, 2 per thread
    const int sm = t >> 2;             // 0..63 : row within half-tile
    const int sk4 = t & 3;             // 0..3  : which float4 along k (BK=16)

    for (int k0 = 0; k0 < D_IN; k0 += BK) {
#pragma unroll
        for (int p = 0; p < 2; ++p) {
            const int m = p * 64 + sm;     // 0..127
            float4 xv = *(const float4*)(X + (size_t)(m0 + m) * D_IN + k0 + sk4 * 4);
            float4 cv = *(const float4*)(C + (size_t)(n0 + m) * D_IN + k0 + sk4 * 4);
            const int col = cpad(m);
#pragma unroll
            for (int i = 0; i < 4; ++i) {
                const int kr = (sk4 * 4 + i) * LDROW + col;
                Xs[kr] = ((const float*)&xv)[i];
                Cs[kr] = ((const float*)&cv)[i];
            }
        }
        __syncthreads();
#pragma unroll
        for (int kk = 0; kk < BK; ++kk) {
            const float* xrow = &Xs[kk * LDROW + 12 * ty];  // 8 contiguous
            const float* crow = &Cs[kk * LDROW + 12 * tx];
            float4 xa0 = *(const float4*)(xrow);
            float4 xa1 = *(const float4*)(xrow + 4);
            float4 cb0 = *(const float4*)(crow);
            float4 cb1 = *(const float4*)(crow + 4);
            const float xs8[8] = {xa0.x, xa0.y, xa0.z, xa0.w,
                                  xa1.x, xa1.y, xa1.z, xa1.w};
            const float cs8[8] = {cb0.x, cb0.y, cb0.z, cb0.w,
                                  cb1.x, cb1.y, cb1.z, cb1.w};
#pragma unroll
            for (int i = 0; i < 8; ++i)
#pragma unroll
                for (int j = 0; j < 8; ++j)
                    acc[i][j] = fmaf(xs8[i], cs8[j], acc[i][j]);
        }
        __syncthreads();
    }

    // Reuse the staging arena for the reduction: [BM][16] f32 + [BM][16] i32
    float* red_d2 = Xs;                 // 2048 floats  (<= 3136)
    int*   red_idx = (int*)Cs;          // 2048 ints

    // Per-thread argmin over its 8 centroids (ascending n, strict <)
#pragma unroll
    for (int i = 0; i < 8; ++i) {
        const int m = m0 + ty * 8 + i;
        const float xq = x_sq[m];
        float bd = INFINITY;
        int   bi = n0 + tx * 8;
#pragma unroll
        for (int j = 0; j < 8; ++j) {
            const int n = n0 + tx * 8 + j;
            const float d2 = (xq - 2.0f * acc[i][j]) + c_sq[n];
            if (d2 < bd) { bd = d2; bi = n; }
        }
        red_d2[(ty * 8 + i) * 16 + tx]  = bd;
        red_idx[(ty * 8 + i) * 16 + tx] = bi;
    }
    __syncthreads();

    // Cross-thread reduce per token row: tx ascending -> n ascending
    if (t < BM) {
        float bd = red_d2[t * 16 + 0];
        int   bi = red_idx[t * 16 + 0];
#pragma unroll
        for (int q = 1; q < 16; ++q) {
            const float d = red_d2[t * 16 + q];
            if (d < bd) { bd = d; bi = red_idx[t * 16 + q]; }
        }
        const int m = m0 + t;
        part_d2[(size_t)m * NT_N + blockIdx.y]  = bd;
        part_idx[(size_t)m * NT_N + blockIdx.y] = bi;
    }
}

// ---------------------------------------------------------------------------
// Final argmin across the NT_N centroid tiles (ascending tile order, strict
// <) fused with the table gather + bias. One block per token.
// ---------------------------------------------------------------------------
__global__ __launch_bounds__(256) void reduce_gather_kernel(
    const float* __restrict__ part_d2,
    const int*   __restrict__ part_idx,
    const float* __restrict__ table,   // [N_CENT][D_OUT]
    const float* __restrict__ bias,    // [D_OUT]
    float* __restrict__ out)           // [N_TOK][D_OUT]
{
    const int m = blockIdx.x;
    float bd = INFINITY;
    int   bi = 0;
#pragma unroll
    for (int q = 0; q < NT_N; ++q) {
        const float d = part_d2[(size_t)m * NT_N + q];
        if (d < bd) { bd = d; bi = part_idx[(size_t)m * NT_N + q]; }
    }
    const float4* tr = (const float4*)(table + (size_t)bi * D_OUT);
    const float4* br = (const float4*)bias;
    float4* orow = (float4*)(out + (size_t)m * D_OUT);
    const int tid = threadIdx.x;          // 1024 floats = 256 float4
    float4 tv = tr[tid];
    float4 bv = br[tid];
    orow[tid] = make_float4(tv.x + bv.x, tv.y + bv.y, tv.z + bv.z, tv.w + bv.w);
}

// ---------------------------------------------------------------------------
// Launch
// ---------------------------------------------------------------------------
extern "C" void kernel_launch(void* const* d_in, const int* in_sizes, int n_in,
                              void* d_out, int out_size, void* d_ws, size_t ws_size,
                              hipStream_t stream)
{
    const float* X     = (const float*)d_in[0];   // [16384,1024]
    const float* C     = (const float*)d_in[1];   // [1024,1024]
    const float* table = (const float*)d_in[2];   // [1024,1024]
    const float* bias  = (const float*)d_in[3];   // [1024]
    float* out = (float*)d_out;

    // Workspace: x_sq[16384] | c_sq[1024] | part_d2[16384*8] | part_idx[16384*8]
    float* x_sq    = (float*)d_ws;
    float* c_sq    = x_sq + N_TOK;
    float* part_d2 = c_sq + N_CENT;
    int*   part_idx = (int*)(part_d2 + (size_t)N_TOK * NT_N);

    rowsq_kernel<<<N_TOK / 4, 256, 0, stream>>>(X, x_sq, N_TOK);
    rowsq_kernel<<<N_CENT / 4, 256, 0, stream>>>(C, c_sq, N_CENT);

    dim3 grid(NT_M, NT_N);
    dist_argmin_kernel<<<grid, 256, 0, stream>>>(X, C, x_sq, c_sq, part_d2, part_idx);

    reduce_gather_kernel<<<N_TOK, 256, 0, stream>>>(part_d2, part_idx, table, bias, out);
}

// Round 3
// 261.954 us; speedup vs baseline: 2.9291x; 2.3863x over previous
//
#include <hip/hip_runtime.h>
#include <math.h>

// Problem constants
#define N_TOK  16384   // B*S
#define D_IN   1024
#define D_OUT  1024
#define N_CENT 1024

// Stage-1 (MFMA) tiling
#define BM 128
#define BN 128
#define BK 32

// Candidate margin: bf16 approx error on d2 is sigma~2e-3, max over 16.8M
// pairs ~1.1e-2. tau=0.05 (~17 sigma of a pairwise error difference)
// guarantees the exact argmin is in {j : d2a[j] <= min_a + tau}.
#define TAU 0.05f

typedef __attribute__((ext_vector_type(8))) short short8;
typedef __attribute__((ext_vector_type(4))) float float4v;
typedef unsigned int u32;
typedef unsigned short u16;

__device__ __forceinline__ void async_copy16(const void* g, void* l) {
    __builtin_amdgcn_global_load_lds(
        (const __attribute__((address_space(1))) u32*)g,
        (__attribute__((address_space(3))) u32*)l, 16, 0, 0);
}

__device__ __forceinline__ u16 f32_to_bf16_rne(float f) {
    u32 u = __float_as_uint(f);
    u32 r = (u + 0x7FFFu + ((u >> 16) & 1u)) >> 16;
    return (u16)r;
}

// ---------------------------------------------------------------------------
// fp32 -> bf16 conversion (RNE), 4 elems/thread
// ---------------------------------------------------------------------------
__global__ __launch_bounds__(256) void convert_bf16_kernel(
    const float* __restrict__ in, u16* __restrict__ out)
{
    const int i = blockIdx.x * 256 + threadIdx.x;
    float4 v = ((const float4*)in)[i];
    ushort4 o;
    o.x = f32_to_bf16_rne(v.x); o.y = f32_to_bf16_rne(v.y);
    o.z = f32_to_bf16_rne(v.z); o.w = f32_to_bf16_rne(v.w);
    ((ushort4*)out)[i] = o;
}

// ---------------------------------------------------------------------------
// Row squared norms (exact fp32). One wave per row.
// ---------------------------------------------------------------------------
__global__ __launch_bounds__(256) void rowsq_kernel(
    const float* __restrict__ x, float* __restrict__ out, int nrows)
{
    const int wave = threadIdx.x >> 6;
    const int lane = threadIdx.x & 63;
    const int row  = blockIdx.x * 4 + wave;
    if (row >= nrows) return;
    const float4* xr = (const float4*)(x + (size_t)row * D_IN);
    float s = 0.f;
#pragma unroll
    for (int i = 0; i < D_IN / 4 / 64; ++i) {
        float4 v = xr[lane + i * 64];
        s += v.x * v.x + v.y * v.y + v.z * v.z + v.w * v.w;
    }
#pragma unroll
    for (int off = 32; off > 0; off >>= 1) s += __shfl_down(s, off);
    if (lane == 0) out[row] = s;
}

// ---------------------------------------------------------------------------
// Stage 1: bf16 MFMA GEMM (G = Xh @ Ch^T) with fused approx-d2 epilogue.
// 256 threads = 4 waves in 2x2; each wave computes a 64x64 subtile via
// 4x4 grid of 16x16x32 MFMAs. LDS staged via global_load_lds width=16,
// with XOR-swizzled k-octets (slot q holds global octet q^(row&3)) to keep
// frag ds_read_b128 at <=2-way bank aliasing (free).
// ---------------------------------------------------------------------------
__global__ __launch_bounds__(256) void gemm_d2_kernel(
    const u16* __restrict__ Xh, const u16* __restrict__ Ch,
    const float* __restrict__ x_sq, const float* __restrict__ c_sq,
    float* __restrict__ D2a)
{
    __shared__ __align__(16) u16 As[BM * BK];   // 8 KB
    __shared__ __align__(16) u16 Bs[BN * BK];   // 8 KB

    const int t  = threadIdx.x;
    const int w  = t >> 6;
    const int l  = t & 63;
    const int wi = w >> 1, wj = w & 1;
    const int m0 = blockIdx.x * BM;
    const int n0 = blockIdx.y * BN;
    const int quad = l >> 4;    // k-octet for A/B frags; row-quad for D
    const int r15  = l & 15;

    float4v acc[4][4];
#pragma unroll
    for (int i = 0; i < 4; ++i)
#pragma unroll
        for (int j = 0; j < 4; ++j)
            acc[i][j] = (float4v){0.f, 0.f, 0.f, 0.f};

    for (int k0 = 0; k0 < D_IN; k0 += BK) {
        // Stage 8 KB per operand: 512 16B slots, 2 rounds x 256 threads.
        // Slot s -> row r=s>>2, lds-octet q=s&3, global octet q^(r&3).
#pragma unroll
        for (int rnd = 0; rnd < 2; ++rnd) {
            const int s = rnd * 256 + t;
            const int r = s >> 2;
            const int q = (s & 3) ^ (r & 3);
            const u16* ga = Xh + (size_t)(m0 + r) * D_IN + k0 + q * 8;
            const u16* gb = Ch + (size_t)(n0 + r) * D_IN + k0 + q * 8;
            async_copy16(ga, As + s * 8);
            async_copy16(gb, Bs + s * 8);
        }
        __syncthreads();

        short8 af[4], bfr[4];
#pragma unroll
        for (int i = 0; i < 4; ++i) {
            const int r = wi * 64 + i * 16 + r15;
            af[i] = *(const short8*)(As + (r * 4 + (quad ^ (r & 3))) * 8);
        }
#pragma unroll
        for (int j = 0; j < 4; ++j) {
            const int r = wj * 64 + j * 16 + r15;
            bfr[j] = *(const short8*)(Bs + (r * 4 + (quad ^ (r & 3))) * 8);
        }
#pragma unroll
        for (int i = 0; i < 4; ++i)
#pragma unroll
            for (int j = 0; j < 4; ++j)
                acc[i][j] = __builtin_amdgcn_mfma_f32_16x16x32_bf16(
                    af[i], bfr[j], acc[i][j], 0, 0, 0);
        __syncthreads();
    }

    // Epilogue: d2a = (x_sq - 2g) + c_sq.
    // D layout (m89-verified): col = lane&15 (=n), row = quad*4 + reg (=m).
    float cqs[4];
#pragma unroll
    for (int j = 0; j < 4; ++j)
        cqs[j] = c_sq[n0 + wj * 64 + j * 16 + r15];

#pragma unroll
    for (int i = 0; i < 4; ++i) {
#pragma unroll
        for (int reg = 0; reg < 4; ++reg) {
            const int m = m0 + wi * 64 + i * 16 + quad * 4 + reg;
            const float xq = x_sq[m];
            float* drow = D2a + (size_t)m * N_CENT + n0 + wj * 64 + r15;
#pragma unroll
            for (int j = 0; j < 4; ++j) {
                const float g = acc[i][j][reg];
                drow[j * 16] = (xq - 2.0f * g) + cqs[j];
            }
        }
    }
}

// ---------------------------------------------------------------------------
// Stage 2: per-token scan of the approx row. One wave per token.
// Finds min1 (value,idx) with numpy first-occurrence semantics (per-lane
// ascending strict <, cross-lane lexicographic), counts candidates within
// TAU; unique candidate -> final answer, else flag for exact rescore.
// ---------------------------------------------------------------------------
__global__ __launch_bounds__(256) void scan_kernel(
    const float* __restrict__ D2a, int* __restrict__ idx_final,
    float* __restrict__ min1val, int* __restrict__ flagged,
    int* __restrict__ counter)
{
    const int wv = threadIdx.x >> 6;
    const int l  = threadIdx.x & 63;
    const int m  = blockIdx.x * 4 + wv;
    const float* row = D2a + (size_t)m * N_CENT;

    float v[16];
#pragma unroll
    for (int i = 0; i < 16; ++i) v[i] = row[i * 64 + l];

    float bv = v[0]; int bj = l;
#pragma unroll
    for (int i = 1; i < 16; ++i) {
        const int j = i * 64 + l;
        if (v[i] < bv) { bv = v[i]; bj = j; }
    }
#pragma unroll
    for (int off = 32; off > 0; off >>= 1) {
        const float ov = __shfl_xor(bv, off);
        const int   oj = __shfl_xor(bj, off);
        if (ov < bv || (ov == bv && oj < bj)) { bv = ov; bj = oj; }
    }

    const float thr = bv + TAU;
    int cnt = 0;
#pragma unroll
    for (int i = 0; i < 16; ++i) cnt += (v[i] <= thr) ? 1 : 0;
#pragma unroll
    for (int off = 32; off > 0; off >>= 1) cnt += __shfl_xor(cnt, off);

    if (l == 0) {
        idx_final[m] = bj;
        if (cnt > 1) {
            min1val[m] = bv;
            const int pos = atomicAdd(counter, 1);
            flagged[pos] = m;
        }
    }
}

// ---------------------------------------------------------------------------
// Stage 3: exact fp32 rescore for flagged tokens. Grid-stride over the
// compacted flag list; per candidate, block-parallel dot + tree reduce,
// lexicographic (value, idx) final pick.
// ---------------------------------------------------------------------------
__global__ __launch_bounds__(256) void rescore_kernel(
    const float* __restrict__ X, const float* __restrict__ C,
    const float* __restrict__ x_sq, const float* __restrict__ c_sq,
    const float* __restrict__ D2a, const float* __restrict__ min1val,
    const int* __restrict__ flagged, const int* __restrict__ counter,
    int* __restrict__ idx_final)
{
    __shared__ __align__(16) float xrow[D_IN];
    __shared__ int  cand[N_CENT];
    __shared__ int  ccount;
    __shared__ float wsum[4];

    const int t = threadIdx.x;
    const int nflag = counter[0];

    for (int fi = blockIdx.x; fi < nflag; fi += gridDim.x) {
        const int m = flagged[fi];
        ((float4*)xrow)[t] = ((const float4*)(X + (size_t)m * D_IN))[t];
        if (t == 0) ccount = 0;
        __syncthreads();

        const float thr = min1val[m] + TAU;
        const float xq  = x_sq[m];
        const float* drow = D2a + (size_t)m * N_CENT;
#pragma unroll
        for (int c = 0; c < 4; ++c) {
            const int n = c * 256 + t;
            if (drow[n] <= thr) {
                const int p = atomicAdd(&ccount, 1);
                cand[p] = n;
            }
        }
        __syncthreads();
        const int ncand = ccount;
        const float4 xv = ((const float4*)xrow)[t];

        float bestv = INFINITY;
        int   bestn = 0x7fffffff;
        for (int ci = 0; ci < ncand; ++ci) {
            const int n = cand[ci];
            const float4 cv = ((const float4*)(C + (size_t)n * D_IN))[t];
            float p = xv.x * cv.x;
            p = fmaf(xv.y, cv.y, p);
            p = fmaf(xv.z, cv.z, p);
            p = fmaf(xv.w, cv.w, p);
#pragma unroll
            for (int off = 32; off > 0; off >>= 1) p += __shfl_xor(p, off);
            if ((t & 63) == 0) wsum[t >> 6] = p;
            __syncthreads();
            const float g = wsum[0] + wsum[1] + wsum[2] + wsum[3];
            const float d2 = (xq - 2.0f * g) + c_sq[n];
            if (d2 < bestv || (d2 == bestv && n < bestn)) { bestv = d2; bestn = n; }
            __syncthreads();
        }
        if (t == 0) idx_final[m] = bestn;
        __syncthreads();
    }
}

// ---------------------------------------------------------------------------
// Final gather + bias. One block per token.
// ---------------------------------------------------------------------------
__global__ __launch_bounds__(256) void gather_kernel(
    const int* __restrict__ idx_final, const float* __restrict__ table,
    const float* __restrict__ bias, float* __restrict__ out)
{
    const int m  = blockIdx.x;
    const int bi = idx_final[m];
    const float4 tv = ((const float4*)(table + (size_t)bi * D_OUT))[threadIdx.x];
    const float4 bv = ((const float4*)bias)[threadIdx.x];
    ((float4*)(out + (size_t)m * D_OUT))[threadIdx.x] =
        make_float4(tv.x + bv.x, tv.y + bv.y, tv.z + bv.z, tv.w + bv.w);
}

// ---------------------------------------------------------------------------
// Launch
// ---------------------------------------------------------------------------
extern "C" void kernel_launch(void* const* d_in, const int* in_sizes, int n_in,
                              void* d_out, int out_size, void* d_ws, size_t ws_size,
                              hipStream_t stream)
{
    const float* X     = (const float*)d_in[0];   // [16384,1024]
    const float* C     = (const float*)d_in[1];   // [1024,1024]
    const float* table = (const float*)d_in[2];   // [1024,1024]
    const float* bias  = (const float*)d_in[3];   // [1024]
    float* out = (float*)d_out;

    // Workspace layout (bytes):
    char* ws = (char*)d_ws;
    float* D2a      = (float*)ws;                              // 64 MB
    u16*   Xh       = (u16*)(ws + 67108864);                   // 32 MB
    u16*   Ch       = (u16*)(ws + 100663296);                  // 2 MB
    float* x_sq     = (float*)(ws + 102760448);                // 64 KB
    float* c_sq     = (float*)(ws + 102825984);                // 4 KB
    int*   idx_fin  = (int*)(ws + 102830080);                  // 64 KB
    float* min1val  = (float*)(ws + 102895616);                // 64 KB
    int*   flagged  = (int*)(ws + 102961152);                  // 64 KB
    int*   counter  = (int*)(ws + 103026688);                  // 4 B

    hipMemsetAsync(counter, 0, 4, stream);

    convert_bf16_kernel<<<(N_TOK * D_IN) / 1024, 256, 0, stream>>>(X, Xh);
    convert_bf16_kernel<<<(N_CENT * D_IN) / 1024, 256, 0, stream>>>(C, Ch);
    rowsq_kernel<<<N_TOK / 4, 256, 0, stream>>>(X, x_sq, N_TOK);
    rowsq_kernel<<<N_CENT / 4, 256, 0, stream>>>(C, c_sq, N_CENT);

    dim3 grid(N_TOK / BM, N_CENT / BN);   // 128 x 8
    gemm_d2_kernel<<<grid, 256, 0, stream>>>(Xh, Ch, x_sq, c_sq, D2a);

    scan_kernel<<<N_TOK / 4, 256, 0, stream>>>(D2a, idx_fin, min1val, flagged, counter);

    rescore_kernel<<<256, 256, 0, stream>>>(X, C, x_sq, c_sq, D2a, min1val,
                                            flagged, counter, idx_fin);

    gather_kernel<<<N_TOK, 256, 0, stream>>>(idx_fin, table, bias, out);
}